// Round 2
// 325.449 us; speedup vs baseline: 1.1699x; 1.1699x over previous
//
#include <hip/hip_runtime.h>
#include <hip/hip_bf16.h>

// Problem constants (fixed by reference)
#define Bn 16
#define Tn 64
#define Nn 256
#define Kn 8
#define dn 8
#define Dn 64
#define TDn 128   // 2*D

typedef __bf16 bf16x8 __attribute__((ext_vector_type(8)));
typedef __bf16 bf16x4 __attribute__((ext_vector_type(4)));
typedef __bf16 bf16x2 __attribute__((ext_vector_type(2)));
typedef float  f32x4  __attribute__((ext_vector_type(4)));

#if __has_builtin(__builtin_amdgcn_exp2f)
#define EXP2F(x) __builtin_amdgcn_exp2f(x)
#else
#define EXP2F(x) exp2f(x)
#endif

__device__ __forceinline__ float geluf(float x) {
    // exact erf GELU (torch F.gelu default)
    return 0.5f * x * (1.0f + erff(x * 0.70710678118654752440f));
}

__device__ __forceinline__ bf16x8 bzero8() {
    bf16x8 z;
    #pragma unroll
    for (int e = 0; e < 8; ++e) z[e] = (__bf16)0.0f;
    return z;
}

// ---- Kernel 1: convert all weights fp32 -> bf16 into d_ws (runs every launch; ws re-poisoned) ----
// ws layout (bf16): [0,24576) Wqkv rows 0-63=W12,64-127=W13,128-191=W14 (row=128 k)
//                   [24576,28672) W15 [64][64]; [28672,32768) W16 [64][64]
__global__ void convert_weights(const float* __restrict__ W12, const float* __restrict__ W13,
                                const float* __restrict__ W14, const float* __restrict__ W15,
                                const float* __restrict__ W16, __bf16* __restrict__ ws)
{
    const int i = blockIdx.x * 256 + threadIdx.x;   // 0..32767
    float v;
    if      (i < 8192)  v = W12[i];
    else if (i < 16384) v = W13[i - 8192];
    else if (i < 24576) v = W14[i - 16384];
    else if (i < 28672) v = W15[i - 24576];
    else                v = W16[i - 28672];
    ws[i] = (__bf16)v;
}

// ---- MFMA attention tile: S^T = K.Q^T for tq-tile J, softmax rows, out^T = V^T.P^T ----
// All indices compile-time static (template J) to keep arrays in registers.
// C/D layout (verified by this kernel's phase 2): col = lane&15, row = (lane>>4)*4 + r.
// S^T tile (i,J): lane cl = tq (within tile J), reg (quad,r) = tk (within tile i).
template <int J>
__device__ __forceinline__ void attn_tile(__bf16 (*qs)[72], __bf16 (*Ps)[72],
                                          bf16x8 kf0, bf16x8 kf1, bf16x8 kf2, bf16x8 kf3,
                                          bf16x8 vf0, bf16x8 vf1,
                                          int hc, int cl, int quad, int kb)
{
    // Q B-frag for tq-tile J: lane cl reads Q[16J+cl][d 0..7] (quad 0), quads 1-3 zero-pad K.
    bf16x8 qf = bzero8();
    if (quad == 0) qf = *reinterpret_cast<const bf16x8*>(&qs[16 * J + cl][hc]);

    const f32x4 zc = {0.f, 0.f, 0.f, 0.f};
    f32x4 st[4];
    st[0] = __builtin_amdgcn_mfma_f32_16x16x32_bf16(kf0, qf, zc, 0, 0, 0);
    if constexpr (J >= 1) st[1] = __builtin_amdgcn_mfma_f32_16x16x32_bf16(kf1, qf, zc, 0, 0, 0);
    if constexpr (J >= 2) st[2] = __builtin_amdgcn_mfma_f32_16x16x32_bf16(kf2, qf, zc, 0, 0, 0);
    if constexpr (J >= 3) st[3] = __builtin_amdgcn_mfma_f32_16x16x32_bf16(kf3, qf, zc, 0, 0, 0);

    // Causal mask inside the diagonal tile (i == J): tk-in-tile = 4*quad+r, tq-in-tile = cl.
    #pragma unroll
    for (int r = 0; r < 4; ++r)
        st[J][r] = (4 * quad + r > cl) ? -3.0e38f : st[J][r];

    // Row max: own regs, then cross-quad (tk spread over quads) via shfl_xor 16/32.
    float mx = -3.0e38f;
    #pragma unroll
    for (int i = 0; i <= J; ++i) {
        #pragma unroll
        for (int r = 0; r < 4; ++r) mx = fmaxf(mx, st[i][r]);
    }
    mx = fmaxf(mx, __shfl_xor(mx, 16));
    mx = fmaxf(mx, __shfl_xor(mx, 32));

    // exp2 (q pre-scaled by 1/sqrt(8)*log2e in phase 2) + row sum. Masked -3e38 -> underflow 0.
    float sum = 0.f;
    #pragma unroll
    for (int i = 0; i <= J; ++i) {
        #pragma unroll
        for (int r = 0; r < 4; ++r) {
            const float p = EXP2F(st[i][r] - mx);
            st[i][r] = p;
            sum += p;
        }
    }
    sum += __shfl_xor(sum, 16);
    sum += __shfl_xor(sum, 32);

    // Write unnormalized P (bf16) row-major into the wave-private P-slice:
    // lane (cl,quad) -> P[cl][16*i + 4*quad .. +3], contiguous b64.
    #pragma unroll
    for (int i = 0; i <= J; ++i) {
        bf16x4 pk;
        #pragma unroll
        for (int r = 0; r < 4; ++r) pk[r] = (__bf16)st[i][r];
        *reinterpret_cast<bf16x4*>(&Ps[cl][16 * i + 4 * quad]) = pk;
    }

    // PV: out^T = V^T (A) . P^T (B). B-frag: lane cl reads P[cl][kk*32+kb ..+7] (b128).
    // Cols beyond 16*(J+1) are the per-head zero-init -> contribute 0.
    f32x4 o = {0.f, 0.f, 0.f, 0.f};
    {
        const bf16x8 pf = *reinterpret_cast<const bf16x8*>(&Ps[cl][kb]);
        o = __builtin_amdgcn_mfma_f32_16x16x32_bf16(vf0, pf, o, 0, 0, 0);
    }
    if constexpr (J >= 2) {
        const bf16x8 pf = *reinterpret_cast<const bf16x8*>(&Ps[cl][32 + kb]);
        o = __builtin_amdgcn_mfma_f32_16x16x32_bf16(vf1, pf, o, 0, 0, 0);
    }

    // out^T C-layout: col = cl = tq, row = 4*quad+r = d (d<8 -> quads 0,1 only).
    // Normalize by 1/rowsum (every lane holds its tq's sum after the xor-reduce).
    const float inv = 1.0f / sum;
    if (quad < 2) {
        bf16x4 ov;
        #pragma unroll
        for (int r = 0; r < 4; ++r) ov[r] = (__bf16)(o[r] * inv);
        *reinterpret_cast<bf16x4*>(&qs[16 * J + cl][hc + 4 * quad]) = ov;
    }
}

// ---- Kernel 2: fused block per (b,n); 256 threads = 4 waves ----
// LDS 36,864 B -> 4 blocks/CU (16 waves).
// Regions: [0,18432)  phase 1-2: Hs[64][136] bf16 (17408 B);
//                     phase 2 epilogue onward: vt[64][72] bf16 at 0 (V transposed, row = h*8+d),
//                     P-slices at 9216 (+wv*2304, [16][72] bf16 per wave).
//          [18432,27648) qs[64][72]  (q in phase 2-3, attention output after phase 3)
//          [27648,36864) ks[64][72]  (k in phase 2-3, MLP hidden in phase 4)
__global__ __launch_bounds__(256, 4)
void tam_fused(const float* __restrict__ X,
               const float* __restrict__ STE,
               const float* __restrict__ b12, const float* __restrict__ b13,
               const float* __restrict__ b14, const float* __restrict__ b15,
               const float* __restrict__ b16,
               const __bf16* __restrict__ Wb,   // converted weights in ws
               float* __restrict__ Out)
{
    __shared__ __align__(16) char smem[36864];
    __bf16 (*Hs)[136] = reinterpret_cast<__bf16 (*)[136]>(smem);          // [64][136] (phase 1-2)
    __bf16 (*vt)[72]  = reinterpret_cast<__bf16 (*)[72]>(smem);           // [64][72] overlay: V^T
    __bf16 (*qs)[72]  = reinterpret_cast<__bf16 (*)[72]>(smem + 18432);   // [64][72]
    __bf16 (*ks)[72]  = reinterpret_cast<__bf16 (*)[72]>(smem + 27648);   // [64][72]

    const int bn   = blockIdx.x;
    const int b    = bn >> 8;     // / Nn
    const int n    = bn & 255;    // % Nn
    const int tid  = threadIdx.x;
    const int lane = tid & 63;
    const int wv   = __builtin_amdgcn_readfirstlane(tid >> 6);
    const int cl   = lane & 15;          // MFMA col-in-tile / A-row-in-tile
    const int quad = lane >> 4;
    const int kb   = quad * 8;           // MFMA k-offset (quad*8)
    const int m0   = wv * 16;            // this wave's row-tile

    __bf16 (*Ps)[72] = reinterpret_cast<__bf16 (*)[72]>(smem + 9216 + wv * 2304); // wave-private P

    const __bf16* Wqkv = Wb;             // [192][128]
    const __bf16* W15b = Wb + 24576;     // [64][64]
    const __bf16* W16b = Wb + 28672;     // [64][64]

    // ---------------- Phase 1: stage H = concat(X, STE) row-major, fp32 -> bf16 ----------------
    {
        const size_t base = ((size_t)b * Tn * Nn + n) * Dn;
        for (int t = wv; t < Tn; t += 4) {
            const size_t rb = base + (size_t)t * (Nn * Dn);
            const float2 v2 = (lane < 32)
                ? reinterpret_cast<const float2*>(X + rb)[lane]
                : reinterpret_cast<const float2*>(STE + rb)[lane - 32];
            bf16x2 p; p[0] = (__bf16)v2.x; p[1] = (__bf16)v2.y;
            *reinterpret_cast<bf16x2*>(&Hs[t][2 * lane]) = p;
        }
    }
    __syncthreads();

    // ---------------- Phase 2: qkv = gelu(H @ Wqkv^T + b) via MFMA ----------------
    // q written pre-scaled by 1/sqrt(8)*log2(e) (attention uses exp2 directly).
    // v written TRANSPOSED into vt[h*8+d][t] (contiguous b64 per lane).
    {
        bf16x8 af[4];
        #pragma unroll
        for (int kk = 0; kk < 4; ++kk)
            af[kk] = *reinterpret_cast<const bf16x8*>(&Hs[m0 + cl][kk * 32 + kb]);
        __syncthreads();   // all waves hold A-frags in regs -> region0 reusable (vt / P-slices)

        #pragma unroll 4
        for (int nt = 0; nt < 12; ++nt) {
            const int n0 = nt * 16;
            f32x4 acc = {0.f, 0.f, 0.f, 0.f};
            #pragma unroll
            for (int kk = 0; kk < 4; ++kk) {
                const bf16x8 bf = *reinterpret_cast<const bf16x8*>(
                    &Wqkv[(n0 + cl) * TDn + kk * 32 + kb]);
                acc = __builtin_amdgcn_mfma_f32_16x16x32_bf16(af[kk], bf, acc, 0, 0, 0);
            }
            if (n0 < 64) {
                const float bias = b12[n0 + cl];
                #pragma unroll
                for (int r = 0; r < 4; ++r) {
                    const int row = m0 + 4 * quad + r;   // C/D: col=lane&15, row=quad*4+r
                    qs[row][n0 + cl] = (__bf16)(geluf(acc[r] + bias) * 0.51006951f);
                }
            } else if (n0 < 128) {
                const float bias = b13[n0 - 64 + cl];
                #pragma unroll
                for (int r = 0; r < 4; ++r) {
                    const int row = m0 + 4 * quad + r;
                    ks[row][n0 - 64 + cl] = (__bf16)geluf(acc[r] + bias);
                }
            } else {
                const float bias = b14[n0 - 128 + cl];
                bf16x4 pv;
                #pragma unroll
                for (int r = 0; r < 4; ++r) pv[r] = (__bf16)geluf(acc[r] + bias);
                // col = h*8+d; rows m0+4q..+3 are consecutive t -> contiguous in vt[col][t]
                *reinterpret_cast<bf16x4*>(&vt[n0 - 128 + cl][m0 + 4 * quad]) = pv;
            }
        }
    }
    __syncthreads();

    // ---------------- Phase 3: MFMA attention (S^T orientation), 2 heads per wave ----------
    // Wave wv owns heads {2wv, 2wv+1} = qs/ks/vt columns [16wv,16wv+16): reads/writes are
    // column-disjoint across waves and the P-slice is wave-private -> no internal barriers.
    {
        #pragma unroll
        for (int hh = 0; hh < 2; ++hh) {
            const int h  = 2 * wv + hh;
            const int hc = 8 * h;

            // K A-frags: lane cl = tk row, quad 0 holds d 0..7, quads 1-3 zero-pad K=32.
            bf16x8 kf0 = bzero8(), kf1 = bzero8(), kf2 = bzero8(), kf3 = bzero8();
            if (quad == 0) {
                kf0 = *reinterpret_cast<const bf16x8*>(&ks[ 0 + cl][hc]);
                kf1 = *reinterpret_cast<const bf16x8*>(&ks[16 + cl][hc]);
                kf2 = *reinterpret_cast<const bf16x8*>(&ks[32 + cl][hc]);
                kf3 = *reinterpret_cast<const bf16x8*>(&ks[48 + cl][hc]);
            }
            // V^T A-frags: lane cl = d row (cl<8 real), k = tk = kk*32+kb.
            bf16x8 vf0 = bzero8(), vf1 = bzero8();
            if (cl < 8) {
                vf0 = *reinterpret_cast<const bf16x8*>(&vt[hc + cl][kb]);
                vf1 = *reinterpret_cast<const bf16x8*>(&vt[hc + cl][32 + kb]);
            }
            // Zero P-slice [16][64] once per head (unwritten cols must multiply V as 0).
            // Each quad owns a 16-col block -> TWO bf16x8 stores (R1 bug: only 8 cols zeroed,
            // leaving stale Hs bytes in cols 24-31 / 56-63 read by the J=0 / J=2 PV MFMAs).
            *reinterpret_cast<bf16x8*>(&Ps[cl][16 * quad])     = bzero8();
            *reinterpret_cast<bf16x8*>(&Ps[cl][16 * quad + 8]) = bzero8();

            attn_tile<0>(qs, Ps, kf0, kf1, kf2, kf3, vf0, vf1, hc, cl, quad, kb);
            attn_tile<1>(qs, Ps, kf0, kf1, kf2, kf3, vf0, vf1, hc, cl, quad, kb);
            attn_tile<2>(qs, Ps, kf0, kf1, kf2, kf3, vf0, vf1, hc, cl, quad, kb);
            attn_tile<3>(qs, Ps, kf0, kf1, kf2, kf3, vf0, vf1, hc, cl, quad, kb);
        }
    }
    __syncthreads();

    // ---------------- Phase 4a: hidden = gelu(attn_out @ W15^T + b15) -> ks (MFMA) ----------------
    {
        const bf16x8 a0 = *reinterpret_cast<const bf16x8*>(&qs[m0 + cl][kb]);
        const bf16x8 a1 = *reinterpret_cast<const bf16x8*>(&qs[m0 + cl][32 + kb]);
        #pragma unroll
        for (int nt = 0; nt < 4; ++nt) {
            const int n0 = nt * 16;
            f32x4 acc = {0.f, 0.f, 0.f, 0.f};
            const bf16x8 bf0 = *reinterpret_cast<const bf16x8*>(&W15b[(n0 + cl) * Dn + kb]);
            acc = __builtin_amdgcn_mfma_f32_16x16x32_bf16(a0, bf0, acc, 0, 0, 0);
            const bf16x8 bf1 = *reinterpret_cast<const bf16x8*>(&W15b[(n0 + cl) * Dn + 32 + kb]);
            acc = __builtin_amdgcn_mfma_f32_16x16x32_bf16(a1, bf1, acc, 0, 0, 0);
            const float bias = b15[n0 + cl];
            #pragma unroll
            for (int r = 0; r < 4; ++r) {
                const int row = m0 + 4 * quad + r;
                ks[row][n0 + cl] = (__bf16)geluf(acc[r] + bias);
            }
        }
    }
    // No barrier: wave reads back only its own 16 rows of ks (same-wave DS ops are in-order).

    // ---------------- Phase 4b: out = hidden @ W16^T + b16 -> global fp32 ----------------
    {
        const bf16x8 a0 = *reinterpret_cast<const bf16x8*>(&ks[m0 + cl][kb]);
        const bf16x8 a1 = *reinterpret_cast<const bf16x8*>(&ks[m0 + cl][32 + kb]);
        #pragma unroll
        for (int nt = 0; nt < 4; ++nt) {
            const int n0 = nt * 16;
            f32x4 acc = {0.f, 0.f, 0.f, 0.f};
            const bf16x8 bf0 = *reinterpret_cast<const bf16x8*>(&W16b[(n0 + cl) * Dn + kb]);
            acc = __builtin_amdgcn_mfma_f32_16x16x32_bf16(a0, bf0, acc, 0, 0, 0);
            const bf16x8 bf1 = *reinterpret_cast<const bf16x8*>(&W16b[(n0 + cl) * Dn + 32 + kb]);
            acc = __builtin_amdgcn_mfma_f32_16x16x32_bf16(a1, bf1, acc, 0, 0, 0);
            const float bias = b16[n0 + cl];
            #pragma unroll
            for (int r = 0; r < 4; ++r) {
                const int row = m0 + 4 * quad + r;
                Out[((size_t)(b * Tn + row) * Nn + n) * Dn + n0 + cl] = acc[r] + bias;
            }
        }
    }
}

extern "C" void kernel_launch(void* const* d_in, const int* in_sizes, int n_in,
                              void* d_out, int out_size, void* d_ws, size_t ws_size,
                              hipStream_t stream)
{
    (void)in_sizes; (void)n_in; (void)out_size; (void)ws_size;
    const float* X   = (const float*)d_in[0];
    const float* STE = (const float*)d_in[1];
    const float* W12 = (const float*)d_in[2];
    const float* b12 = (const float*)d_in[3];
    const float* W13 = (const float*)d_in[4];
    const float* b13 = (const float*)d_in[5];
    const float* W14 = (const float*)d_in[6];
    const float* b14 = (const float*)d_in[7];
    const float* W15 = (const float*)d_in[8];
    const float* b15 = (const float*)d_in[9];
    const float* W16 = (const float*)d_in[10];
    const float* b16 = (const float*)d_in[11];
    float* Out = (float*)d_out;
    __bf16* ws = (__bf16*)d_ws;   // needs 65,536 B

    hipLaunchKernelGGL(convert_weights, dim3(128), dim3(256), 0, stream,
                       W12, W13, W14, W15, W16, ws);
    hipLaunchKernelGGL(tam_fused, dim3(Bn * Nn), dim3(256), 0, stream,
                       X, STE, b12, b13, b14, b15, b16, ws, Out);
}

// Round 3
// 277.587 us; speedup vs baseline: 1.3716x; 1.1724x over previous
//
#include <hip/hip_runtime.h>
#include <hip/hip_bf16.h>

// Problem constants (fixed by reference)
#define Bn 16
#define Tn 64
#define Nn 256
#define Kn 8
#define dn 8
#define Dn 64
#define TDn 128   // 2*D

typedef __bf16 bf16x8 __attribute__((ext_vector_type(8)));
typedef __bf16 bf16x4 __attribute__((ext_vector_type(4)));
typedef __bf16 bf16x2 __attribute__((ext_vector_type(2)));
typedef float  f32x4  __attribute__((ext_vector_type(4)));

#if __has_builtin(__builtin_amdgcn_exp2f)
#define EXP2F(x) __builtin_amdgcn_exp2f(x)
#else
#define EXP2F(x) exp2f(x)
#endif

#if __has_builtin(__builtin_amdgcn_rcpf)
#define RCPF(x) __builtin_amdgcn_rcpf(x)
#else
#define RCPF(x) (1.0f / (x))
#endif

// tanh-form GELU via native exp2 + rcp (~10 VALU ops vs ~60 for libm erff).
// gelu(x) = 0.5x(1+tanh(0.79788456(x+0.044715x^3))); max |err| vs exact-erf ~2e-4,
// an order below the bf16 quantization noise downstream.
__device__ __forceinline__ float geluf(float x) {
    const float x2 = x * x;
    // v = 2*log2(e)*u, u = 0.79788456*(x + 0.044715*x^3)
    const float v = x * fmaf(0.10294342f, x2, 2.30220920f);
    const float w = EXP2F(-fabsf(v));          // e^{-2|u|}
    const float r = RCPF(1.0f + w);
    const float t = (1.0f - w) * r;            // tanh(|u|)
    return fmaf(0.5f * fabsf(x), t, 0.5f * x); // 0.5x + 0.5|x|tanh(|u|)
}

__device__ __forceinline__ bf16x8 bzero8() {
    bf16x8 z;
    #pragma unroll
    for (int e = 0; e < 8; ++e) z[e] = (__bf16)0.0f;
    return z;
}

// ---- Kernel 1: convert all weights fp32 -> bf16 into d_ws (runs every launch; ws re-poisoned) ----
// ws layout (bf16): [0,24576) Wqkv rows 0-63=W12,64-127=W13,128-191=W14 (row=128 k)
//                   [24576,28672) W15 [64][64]; [28672,32768) W16 [64][64]
__global__ void convert_weights(const float* __restrict__ W12, const float* __restrict__ W13,
                                const float* __restrict__ W14, const float* __restrict__ W15,
                                const float* __restrict__ W16, __bf16* __restrict__ ws)
{
    const int i = blockIdx.x * 256 + threadIdx.x;   // 0..32767
    float v;
    if      (i < 8192)  v = W12[i];
    else if (i < 16384) v = W13[i - 8192];
    else if (i < 24576) v = W14[i - 16384];
    else if (i < 28672) v = W15[i - 24576];
    else                v = W16[i - 28672];
    ws[i] = (__bf16)v;
}

// ---- MFMA attention tile: S^T = K.Q^T for tq-tile J, softmax rows, out^T = V^T.P^T ----
// All indices compile-time static (template J) to keep arrays in registers.
// C/D layout (verified by this kernel's phase 2): col = lane&15, row = (lane>>4)*4 + r.
// S^T tile (i,J): lane cl = tq (within tile J), reg (quad,r) = tk (within tile i).
template <int J>
__device__ __forceinline__ void attn_tile(__bf16 (*qs)[72], __bf16 (*Ps)[72],
                                          bf16x8 kf0, bf16x8 kf1, bf16x8 kf2, bf16x8 kf3,
                                          bf16x8 vf0, bf16x8 vf1,
                                          int hc, int cl, int quad, int kb)
{
    // Q B-frag for tq-tile J: lane cl reads Q[16J+cl][d 0..7] (quad 0), quads 1-3 zero-pad K.
    bf16x8 qf = bzero8();
    if (quad == 0) qf = *reinterpret_cast<const bf16x8*>(&qs[16 * J + cl][hc]);

    const f32x4 zc = {0.f, 0.f, 0.f, 0.f};
    f32x4 st[4];
    st[0] = __builtin_amdgcn_mfma_f32_16x16x32_bf16(kf0, qf, zc, 0, 0, 0);
    if constexpr (J >= 1) st[1] = __builtin_amdgcn_mfma_f32_16x16x32_bf16(kf1, qf, zc, 0, 0, 0);
    if constexpr (J >= 2) st[2] = __builtin_amdgcn_mfma_f32_16x16x32_bf16(kf2, qf, zc, 0, 0, 0);
    if constexpr (J >= 3) st[3] = __builtin_amdgcn_mfma_f32_16x16x32_bf16(kf3, qf, zc, 0, 0, 0);

    // Causal mask inside the diagonal tile (i == J): tk-in-tile = 4*quad+r, tq-in-tile = cl.
    #pragma unroll
    for (int r = 0; r < 4; ++r)
        st[J][r] = (4 * quad + r > cl) ? -3.0e38f : st[J][r];

    // Row max: own regs, then cross-quad (tk spread over quads) via shfl_xor 16/32.
    float mx = -3.0e38f;
    #pragma unroll
    for (int i = 0; i <= J; ++i) {
        #pragma unroll
        for (int r = 0; r < 4; ++r) mx = fmaxf(mx, st[i][r]);
    }
    mx = fmaxf(mx, __shfl_xor(mx, 16));
    mx = fmaxf(mx, __shfl_xor(mx, 32));

    // exp2 (q pre-scaled by 1/sqrt(8)*log2e in phase 2) + row sum. Masked -3e38 -> underflow 0.
    float sum = 0.f;
    #pragma unroll
    for (int i = 0; i <= J; ++i) {
        #pragma unroll
        for (int r = 0; r < 4; ++r) {
            const float p = EXP2F(st[i][r] - mx);
            st[i][r] = p;
            sum += p;
        }
    }
    sum += __shfl_xor(sum, 16);
    sum += __shfl_xor(sum, 32);

    // Write unnormalized P (bf16) row-major into the wave-private P-slice:
    // lane (cl,quad) -> P[cl][16*i + 4*quad .. +3], contiguous b64.
    #pragma unroll
    for (int i = 0; i <= J; ++i) {
        bf16x4 pk;
        #pragma unroll
        for (int r = 0; r < 4; ++r) pk[r] = (__bf16)st[i][r];
        *reinterpret_cast<bf16x4*>(&Ps[cl][16 * i + 4 * quad]) = pk;
    }

    // PV: out^T = V^T (A) . P^T (B). B-frag: lane cl reads P[cl][kk*32+kb ..+7] (b128).
    // Cols beyond 16*(J+1) are the per-head zero-init -> contribute 0.
    f32x4 o = {0.f, 0.f, 0.f, 0.f};
    {
        const bf16x8 pf = *reinterpret_cast<const bf16x8*>(&Ps[cl][kb]);
        o = __builtin_amdgcn_mfma_f32_16x16x32_bf16(vf0, pf, o, 0, 0, 0);
    }
    if constexpr (J >= 2) {
        const bf16x8 pf = *reinterpret_cast<const bf16x8*>(&Ps[cl][32 + kb]);
        o = __builtin_amdgcn_mfma_f32_16x16x32_bf16(vf1, pf, o, 0, 0, 0);
    }

    // out^T C-layout: col = cl = tq, row = 4*quad+r = d (d<8 -> quads 0,1 only).
    // Normalize by 1/rowsum (every lane holds its tq's sum after the xor-reduce).
    const float inv = RCPF(sum);   // sum >= 1 (diagonal term exp2(0)=1)
    if (quad < 2) {
        bf16x4 ov;
        #pragma unroll
        for (int r = 0; r < 4; ++r) ov[r] = (__bf16)(o[r] * inv);
        *reinterpret_cast<bf16x4*>(&qs[16 * J + cl][hc + 4 * quad]) = ov;
    }
}

// ---- Kernel 2: fused block per (b,n); 256 threads = 4 waves ----
// LDS 36,864 B -> 4 blocks/CU (16 waves).
// Regions: [0,9216)      vt[64][72] bf16 (V transposed, row = h*8+d)
//          [9216,18432)  P-slices (+wv*2304, [16][72] bf16 per wave)
//          [18432,27648) qs[64][72]  (q in phase 2-3, attention output after phase 3)
//          [27648,36864) ks[64][72]  (k in phase 2-3, MLP hidden in phase 4)
// No H staging: Phase-2 A-frags are loaded straight from global X/STE (wave-private rows).
__global__ __launch_bounds__(256, 4)
void tam_fused(const float* __restrict__ X,
               const float* __restrict__ STE,
               const float* __restrict__ b12, const float* __restrict__ b13,
               const float* __restrict__ b14, const float* __restrict__ b15,
               const float* __restrict__ b16,
               const __bf16* __restrict__ Wb,   // converted weights in ws
               float* __restrict__ Out)
{
    __shared__ __align__(16) char smem[36864];
    __bf16 (*vt)[72]  = reinterpret_cast<__bf16 (*)[72]>(smem);           // [64][72]: V^T
    __bf16 (*qs)[72]  = reinterpret_cast<__bf16 (*)[72]>(smem + 18432);   // [64][72]
    __bf16 (*ks)[72]  = reinterpret_cast<__bf16 (*)[72]>(smem + 27648);   // [64][72]

    const int bn   = blockIdx.x;
    const int b    = bn >> 8;     // / Nn
    const int n    = bn & 255;    // % Nn
    const int tid  = threadIdx.x;
    const int lane = tid & 63;
    const int wv   = __builtin_amdgcn_readfirstlane(tid >> 6);
    const int cl   = lane & 15;          // MFMA col-in-tile / A-row-in-tile
    const int quad = lane >> 4;
    const int kb   = quad * 8;           // MFMA k-offset (quad*8)
    const int m0   = wv * 16;            // this wave's row-tile

    __bf16 (*Ps)[72] = reinterpret_cast<__bf16 (*)[72]>(smem + 9216 + wv * 2304); // wave-private P

    const __bf16* Wqkv = Wb;             // [192][128]
    const __bf16* W15b = Wb + 24576;     // [64][64]
    const __bf16* W16b = Wb + 28672;     // [64][64]

    // ---------------- Phase 2: qkv = gelu(H @ Wqkv^T + b) via MFMA ----------------
    // A-frags direct from global: lane (cl,quad) needs H[m0+cl][kk*32 + quad*8 .. +8];
    // k<64 -> X row slice, k>=64 -> STE row slice. Two float4 loads + cvt per frag.
    // q written pre-scaled by 1/sqrt(8)*log2(e) (attention uses exp2 directly).
    // v written TRANSPOSED into vt[h*8+d][t] (contiguous b64 per lane).
    {
        bf16x8 af[4];
        {
            const int t = m0 + cl;
            const size_t rb = (((size_t)b * Tn + t) * Nn + n) * (size_t)Dn;
            const float4* Xr = reinterpret_cast<const float4*>(X + rb);
            const float4* Sr = reinterpret_cast<const float4*>(STE + rb);
            #pragma unroll
            for (int kk = 0; kk < 4; ++kk) {
                const float4* src = (kk < 2) ? Xr : Sr;
                const int fi = (kk & 1) * 8 + quad * 2;
                const float4 f0 = src[fi];
                const float4 f1 = src[fi + 1];
                bf16x8 a;
                a[0] = (__bf16)f0.x; a[1] = (__bf16)f0.y;
                a[2] = (__bf16)f0.z; a[3] = (__bf16)f0.w;
                a[4] = (__bf16)f1.x; a[5] = (__bf16)f1.y;
                a[6] = (__bf16)f1.z; a[7] = (__bf16)f1.w;
                af[kk] = a;
            }
        }

        #pragma unroll
        for (int nt = 0; nt < 12; ++nt) {
            const int n0 = nt * 16;
            f32x4 acc = {0.f, 0.f, 0.f, 0.f};
            #pragma unroll
            for (int kk = 0; kk < 4; ++kk) {
                const bf16x8 bf = *reinterpret_cast<const bf16x8*>(
                    &Wqkv[(n0 + cl) * TDn + kk * 32 + kb]);
                acc = __builtin_amdgcn_mfma_f32_16x16x32_bf16(af[kk], bf, acc, 0, 0, 0);
            }
            if (n0 < 64) {
                const float bias = b12[n0 + cl];
                #pragma unroll
                for (int r = 0; r < 4; ++r) {
                    const int row = m0 + 4 * quad + r;   // C/D: col=lane&15, row=quad*4+r
                    qs[row][n0 + cl] = (__bf16)(geluf(acc[r] + bias) * 0.51006951f);
                }
            } else if (n0 < 128) {
                const float bias = b13[n0 - 64 + cl];
                #pragma unroll
                for (int r = 0; r < 4; ++r) {
                    const int row = m0 + 4 * quad + r;
                    ks[row][n0 - 64 + cl] = (__bf16)geluf(acc[r] + bias);
                }
            } else {
                const float bias = b14[n0 - 128 + cl];
                bf16x4 pv;
                #pragma unroll
                for (int r = 0; r < 4; ++r) pv[r] = (__bf16)geluf(acc[r] + bias);
                // col = h*8+d; rows m0+4q..+3 are consecutive t -> contiguous in vt[col][t]
                *reinterpret_cast<bf16x4*>(&vt[n0 - 128 + cl][m0 + 4 * quad]) = pv;
            }
        }
    }
    __syncthreads();

    // ---------------- Phase 3: MFMA attention (S^T orientation), 2 heads per wave ----------
    // Wave wv owns heads {2wv, 2wv+1} = qs/ks/vt columns [16wv,16wv+16): reads/writes are
    // column-disjoint across waves and the P-slice is wave-private -> no internal barriers.
    {
        #pragma unroll
        for (int hh = 0; hh < 2; ++hh) {
            const int h  = 2 * wv + hh;
            const int hc = 8 * h;

            // K A-frags: lane cl = tk row, quad 0 holds d 0..7, quads 1-3 zero-pad K=32.
            bf16x8 kf0 = bzero8(), kf1 = bzero8(), kf2 = bzero8(), kf3 = bzero8();
            if (quad == 0) {
                kf0 = *reinterpret_cast<const bf16x8*>(&ks[ 0 + cl][hc]);
                kf1 = *reinterpret_cast<const bf16x8*>(&ks[16 + cl][hc]);
                kf2 = *reinterpret_cast<const bf16x8*>(&ks[32 + cl][hc]);
                kf3 = *reinterpret_cast<const bf16x8*>(&ks[48 + cl][hc]);
            }
            // V^T A-frags: lane cl = d row (cl<8 real), k = tk = kk*32+kb.
            bf16x8 vf0 = bzero8(), vf1 = bzero8();
            if (cl < 8) {
                vf0 = *reinterpret_cast<const bf16x8*>(&vt[hc + cl][kb]);
                vf1 = *reinterpret_cast<const bf16x8*>(&vt[hc + cl][32 + kb]);
            }
            // Zero P-slice [16][64] once per head (unwritten cols must multiply V as 0).
            // Each quad owns a 16-col block -> TWO bf16x8 stores.
            *reinterpret_cast<bf16x8*>(&Ps[cl][16 * quad])     = bzero8();
            *reinterpret_cast<bf16x8*>(&Ps[cl][16 * quad + 8]) = bzero8();

            attn_tile<0>(qs, Ps, kf0, kf1, kf2, kf3, vf0, vf1, hc, cl, quad, kb);
            attn_tile<1>(qs, Ps, kf0, kf1, kf2, kf3, vf0, vf1, hc, cl, quad, kb);
            attn_tile<2>(qs, Ps, kf0, kf1, kf2, kf3, vf0, vf1, hc, cl, quad, kb);
            attn_tile<3>(qs, Ps, kf0, kf1, kf2, kf3, vf0, vf1, hc, cl, quad, kb);
        }
    }
    __syncthreads();

    // ---------------- Phase 4a: hidden = gelu(attn_out @ W15^T + b15) -> ks (MFMA) ----------------
    {
        const bf16x8 a0 = *reinterpret_cast<const bf16x8*>(&qs[m0 + cl][kb]);
        const bf16x8 a1 = *reinterpret_cast<const bf16x8*>(&qs[m0 + cl][32 + kb]);
        #pragma unroll
        for (int nt = 0; nt < 4; ++nt) {
            const int n0 = nt * 16;
            f32x4 acc = {0.f, 0.f, 0.f, 0.f};
            const bf16x8 bf0 = *reinterpret_cast<const bf16x8*>(&W15b[(n0 + cl) * Dn + kb]);
            acc = __builtin_amdgcn_mfma_f32_16x16x32_bf16(a0, bf0, acc, 0, 0, 0);
            const bf16x8 bf1 = *reinterpret_cast<const bf16x8*>(&W15b[(n0 + cl) * Dn + 32 + kb]);
            acc = __builtin_amdgcn_mfma_f32_16x16x32_bf16(a1, bf1, acc, 0, 0, 0);
            const float bias = b15[n0 + cl];
            #pragma unroll
            for (int r = 0; r < 4; ++r) {
                const int row = m0 + 4 * quad + r;
                ks[row][n0 + cl] = (__bf16)geluf(acc[r] + bias);
            }
        }
    }
    // No barrier: wave reads back only its own 16 rows of ks (same-wave DS ops are in-order).

    // ---------------- Phase 4b: out = hidden @ W16^T + b16 -> global fp32 ----------------
    {
        const bf16x8 a0 = *reinterpret_cast<const bf16x8*>(&ks[m0 + cl][kb]);
        const bf16x8 a1 = *reinterpret_cast<const bf16x8*>(&ks[m0 + cl][32 + kb]);
        #pragma unroll
        for (int nt = 0; nt < 4; ++nt) {
            const int n0 = nt * 16;
            f32x4 acc = {0.f, 0.f, 0.f, 0.f};
            const bf16x8 bf0 = *reinterpret_cast<const bf16x8*>(&W16b[(n0 + cl) * Dn + kb]);
            acc = __builtin_amdgcn_mfma_f32_16x16x32_bf16(a0, bf0, acc, 0, 0, 0);
            const bf16x8 bf1 = *reinterpret_cast<const bf16x8*>(&W16b[(n0 + cl) * Dn + 32 + kb]);
            acc = __builtin_amdgcn_mfma_f32_16x16x32_bf16(a1, bf1, acc, 0, 0, 0);
            const float bias = b16[n0 + cl];
            #pragma unroll
            for (int r = 0; r < 4; ++r) {
                const int row = m0 + 4 * quad + r;
                Out[((size_t)(b * Tn + row) * Nn + n) * Dn + n0 + cl] = acc[r] + bias;
            }
        }
    }
}

extern "C" void kernel_launch(void* const* d_in, const int* in_sizes, int n_in,
                              void* d_out, int out_size, void* d_ws, size_t ws_size,
                              hipStream_t stream)
{
    (void)in_sizes; (void)n_in; (void)out_size; (void)ws_size;
    const float* X   = (const float*)d_in[0];
    const float* STE = (const float*)d_in[1];
    const float* W12 = (const float*)d_in[2];
    const float* b12 = (const float*)d_in[3];
    const float* W13 = (const float*)d_in[4];
    const float* b13 = (const float*)d_in[5];
    const float* W14 = (const float*)d_in[6];
    const float* b14 = (const float*)d_in[7];
    const float* W15 = (const float*)d_in[8];
    const float* b15 = (const float*)d_in[9];
    const float* W16 = (const float*)d_in[10];
    const float* b16 = (const float*)d_in[11];
    float* Out = (float*)d_out;
    __bf16* ws = (__bf16*)d_ws;   // needs 65,536 B

    hipLaunchKernelGGL(convert_weights, dim3(128), dim3(256), 0, stream,
                       W12, W13, W14, W15, W16, ws);
    hipLaunchKernelGGL(tam_fused, dim3(Bn * Nn), dim3(256), 0, stream,
                       X, STE, b12, b13, b14, b15, b16, ws, Out);
}